// Round 2
// baseline (267.645 us; speedup 1.0000x reference)
//
#include <hip/hip_runtime.h>

#define WIRES   12
#define NSTATE  4096          // 2^12
#define QDEPTH  8
#define BLOCK   256
#define PER_T   (NSTATE / BLOCK)   // 16 amplitudes per thread

// One block = one batch element. Entire 32KB state lives in LDS.
// Rot gate on wire w acts on bit (11-w) of the flat index.
// CNOT ring of a layer is folded into a single GF(2)-linear permutation:
//   state_after[i] = state_before[F(i)],  F = g_0∘g_1∘...∘g_11 (g_11 innermost)
// Norm/unnorm cancels (circuit is linear); harness compares float32 view
// (real part) of the complex output -> write_mode 0 emits Re only.
__global__ __launch_bounds__(BLOCK, 4) void qsim_kernel(
    const float* __restrict__ x,
    const float* __restrict__ wts,
    const int*   __restrict__ reps_ptr,
    float*       __restrict__ out,
    int write_mode)
{
    __shared__ float2 st[NSTATE];                  // 32 KB
    __shared__ float  mats[QDEPTH * WIRES][8];     // 3 KB

    const int tid = threadIdx.x;
    const int b   = blockIdx.x;

    // ---- rotation matrices from tanh(weights), one per thread (96) ----
    if (tid < QDEPTH * WIRES) {
        float phi   = tanhf(wts[tid * 3 + 0]);
        float theta = tanhf(wts[tid * 3 + 1]);
        float omega = tanhf(wts[tid * 3 + 2]);
        float c  = cosf(theta * 0.5f);
        float s  = sinf(theta * 0.5f);
        float a  = 0.5f * (phi + omega);
        float bm = 0.5f * (phi - omega);
        float ca = cosf(a),  sa = sinf(a);
        float cb = cosf(bm), sb = sinf(bm);
        mats[tid][0] =  c * ca;   // U00 = e^{-ia} c
        mats[tid][1] = -c * sa;
        mats[tid][2] = -s * cb;   // U01 = -conj(em) s
        mats[tid][3] = -s * sb;
        mats[tid][4] =  s * cb;   // U10 = em s
        mats[tid][5] = -s * sb;
        mats[tid][6] =  c * ca;   // U11 = conj(ep) c
        mats[tid][7] =  c * sa;
    }

    // ---- load state ----
    const float* xb = x + (size_t)b * NSTATE;
    #pragma unroll
    for (int k = 0; k < PER_T; ++k) {
        int i = tid + k * BLOCK;
        st[i] = make_float2(xb[i], 0.0f);
    }
    __syncthreads();

    const int reps = reps_ptr[0];
    for (int rep = 0; rep < reps; ++rep) {
        for (int l = 0; l < QDEPTH; ++l) {
            // ---------- 12 single-qubit Rot gates ----------
            for (int wi = 0; wi < WIRES; ++wi) {
                const float* m = mats[l * WIRES + wi];
                const float u00r = m[0], u00i = m[1], u01r = m[2], u01i = m[3];
                const float u10r = m[4], u10i = m[5], u11r = m[6], u11i = m[7];
                const int bp   = 11 - wi;
                const int mask = 1 << bp;
                #pragma unroll
                for (int k = 0; k < (NSTATE / 2) / BLOCK; ++k) {
                    int p  = tid + k * BLOCK;
                    int i0 = ((p >> bp) << (bp + 1)) | (p & (mask - 1));
                    int i1 = i0 | mask;
                    float2 s0 = st[i0], s1 = st[i1];
                    float2 n0, n1;
                    n0.x = u00r * s0.x - u00i * s0.y + u01r * s1.x - u01i * s1.y;
                    n0.y = u00r * s0.y + u00i * s0.x + u01r * s1.y + u01i * s1.x;
                    n1.x = u10r * s0.x - u10i * s0.y + u11r * s1.x - u11i * s1.y;
                    n1.y = u10r * s0.y + u10i * s0.x + u11r * s1.y + u11i * s1.x;
                    st[i0] = n0;
                    st[i1] = n1;
                }
                __syncthreads();
            }

            // ---------- CNOT ring as one linear permutation ----------
            const int r = (l % (WIRES - 1)) + 1;
            int cols[WIRES];
            #pragma unroll
            for (int j = 0; j < WIRES; ++j) {
                int v = 1 << j;
                for (int k = WIRES - 1; k >= 0; --k) {   // g11 innermost
                    int bc = 11 - k;                     // control bit
                    int bt = 11 - ((k + r) % WIRES);     // target bit
                    v ^= ((v >> bc) & 1) << bt;
                }
                cols[j] = v;
            }
            int Ft = 0;
            #pragma unroll
            for (int j = 0; j < 8; ++j)
                if ((tid >> j) & 1) Ft ^= cols[j];

            float2 tmp[PER_T];
            #pragma unroll
            for (int k = 0; k < PER_T; ++k) {
                int fhi = ((k & 1) ? cols[8]  : 0) ^
                          ((k & 2) ? cols[9]  : 0) ^
                          ((k & 4) ? cols[10] : 0) ^
                          ((k & 8) ? cols[11] : 0);
                tmp[k] = st[Ft ^ fhi];
            }
            __syncthreads();
            #pragma unroll
            for (int k = 0; k < PER_T; ++k)
                st[tid + (k << 8)] = tmp[k];
            __syncthreads();
        }
    }

    // ---- write out ----
    if (write_mode == 0) {
        // harness views complex output as float32 real part: out_size = B*4096
        float* ob = out + (size_t)b * NSTATE;
        #pragma unroll
        for (int k = 0; k < PER_T; ++k) {
            int i = tid + k * BLOCK;
            ob[i] = st[i].x;
        }
    } else {
        // interleaved re,im: out_size = 2*B*4096
        float2* ob = (float2*)out + (size_t)b * NSTATE;
        #pragma unroll
        for (int k = 0; k < PER_T; ++k) {
            int i = tid + k * BLOCK;
            ob[i] = st[i];
        }
    }
}

extern "C" void kernel_launch(void* const* d_in, const int* in_sizes, int n_in,
                              void* d_out, int out_size, void* d_ws, size_t ws_size,
                              hipStream_t stream) {
    const float* x    = (const float*)d_in[0];
    const float* wts  = (const float*)d_in[1];
    const int*   reps = (const int*)d_in[2];
    float*       out  = (float*)d_out;
    (void)in_sizes; (void)n_in; (void)d_ws; (void)ws_size;

    // If d_out holds 2 floats per amplitude, write interleaved complex;
    // otherwise (out_size == B*4096) write the real part only.
    const int write_mode = (out_size >= 2 * 1024 * NSTATE) ? 1 : 0;

    qsim_kernel<<<1024, BLOCK, 0, stream>>>(x, wts, reps, out, write_mode);
}

// Round 3
// 226.983 us; speedup vs baseline: 1.1791x; 1.1791x over previous
//
#include <hip/hip_runtime.h>

#define WIRES   12
#define NSTATE  4096          // 2^12
#define QDEPTH  8
#define BLOCK   256
#define PER_T   16            // amplitudes per thread (4 local index bits)

// XOR swizzle on float2-granular LDS index: spreads every access pattern
// uniformly over the 16 float2 bank-columns (4 lanes/column = b64 minimum).
__device__ __forceinline__ int swz(int i) { return i ^ ((i >> 4) & 0xF); }

// Apply 2x2 complex gate on local register bit P (P compile-time => static reg idx).
template<int P>
__device__ __forceinline__ void gate(float2 r[PER_T], const float* __restrict__ m)
{
    const float u00r = m[0], u00i = m[1], u01r = m[2], u01i = m[3];
    const float u10r = m[4], u10i = m[5], u11r = m[6], u11i = m[7];
    #pragma unroll
    for (int pr = 0; pr < 8; ++pr) {
        const int k0 = ((pr >> P) << (P + 1)) | (pr & ((1 << P) - 1));
        const int k1 = k0 | (1 << P);
        const float2 s0 = r[k0], s1 = r[k1];
        r[k0].x = u00r*s0.x - u00i*s0.y + u01r*s1.x - u01i*s1.y;
        r[k0].y = u00r*s0.y + u00i*s0.x + u01r*s1.y + u01i*s1.x;
        r[k1].x = u10r*s0.x - u10i*s0.y + u11r*s1.x - u11i*s1.y;
        r[k1].y = u10r*s0.y + u10i*s0.x + u11r*s1.y + u11i*s1.x;
    }
}

// One block = one batch element. State lives in 16 float2 registers/thread;
// LDS used only for the 3 bit-remap round-trips per layer. The CNOT ring is
// folded into one GF(2)-linear permutation F applied during the last remap.
__global__ __launch_bounds__(BLOCK, 4) void qsim_kernel(
    const float* __restrict__ x,
    const float* __restrict__ wts,
    const int*   __restrict__ reps_ptr,
    float*       __restrict__ out,
    int write_mode)
{
    __shared__ float2 st[NSTATE];                  // 32 KB
    __shared__ float  mats[QDEPTH * WIRES][8];     // 3 KB

    const int tid = threadIdx.x;
    const int b   = blockIdx.x;
    const int thi = tid >> 4, tlo = tid & 15;

    // ---- rotation matrices from tanh(weights), one per thread (96) ----
    if (tid < QDEPTH * WIRES) {
        float phi   = tanhf(wts[tid * 3 + 0]);
        float theta = tanhf(wts[tid * 3 + 1]);
        float omega = tanhf(wts[tid * 3 + 2]);
        float c  = cosf(theta * 0.5f);
        float s  = sinf(theta * 0.5f);
        float a  = 0.5f * (phi + omega);
        float bm = 0.5f * (phi - omega);
        float ca = cosf(a),  sa = sinf(a);
        float cb = cosf(bm), sb = sinf(bm);
        mats[tid][0] =  c * ca;   // U00 = e^{-ia} c
        mats[tid][1] = -c * sa;
        mats[tid][2] = -s * cb;   // U01 = -conj(em) s
        mats[tid][3] = -s * sb;
        mats[tid][4] =  s * cb;   // U10 = em s
        mats[tid][5] = -s * sb;
        mats[tid][6] =  c * ca;   // U11 = conj(ep) c
        mats[tid][7] =  c * sa;
    }

    // ---- load 16 amplitudes straight to registers (norm cancels: linear) ----
    float2 r[PER_T];
    const float4* xb4 = (const float4*)(x + (size_t)b * NSTATE);
    #pragma unroll
    for (int c4 = 0; c4 < 4; ++c4) {
        float4 v = xb4[tid * 4 + c4];
        r[4*c4+0] = make_float2(v.x, 0.f);
        r[4*c4+1] = make_float2(v.y, 0.f);
        r[4*c4+2] = make_float2(v.z, 0.f);
        r[4*c4+3] = make_float2(v.w, 0.f);
    }
    __syncthreads();   // mats ready

    const int reps = reps_ptr[0];
    for (int rep = 0; rep < reps; ++rep)
    for (int l = 0; l < QDEPTH; ++l) {
        const float* M = &mats[l * WIRES][0];

        // ---- Phase A: canonical layout, index bits 3..0 local = wires 8..11
        gate<3>(r, M + 8*8);
        gate<2>(r, M + 9*8);
        gate<1>(r, M + 10*8);
        gate<0>(r, M + 11*8);

        // ---- RT1: localize index bits 4..7
        #pragma unroll
        for (int k = 0; k < PER_T; ++k) st[swz((tid << 4) | k)] = r[k];
        __syncthreads();
        #pragma unroll
        for (int k = 0; k < PER_T; ++k) r[k] = st[swz((thi << 8) | (k << 4) | tlo)];
        __syncthreads();

        // ---- Phase B: bits 7..4 local = wires 4..7 (wire w -> P = 7-w)
        gate<3>(r, M + 4*8);
        gate<2>(r, M + 5*8);
        gate<1>(r, M + 6*8);
        gate<0>(r, M + 7*8);

        // ---- RT2: localize index bits 8..11
        #pragma unroll
        for (int k = 0; k < PER_T; ++k) st[swz((thi << 8) | (k << 4) | tlo)] = r[k];
        __syncthreads();
        #pragma unroll
        for (int k = 0; k < PER_T; ++k) r[k] = st[swz((k << 8) | tid)];
        __syncthreads();

        // ---- Phase C: bits 11..8 local = wires 0..3 (wire w -> P = 3-w)
        gate<3>(r, M + 0*8);
        gate<2>(r, M + 1*8);
        gate<1>(r, M + 2*8);
        gate<0>(r, M + 3*8);

        // ---- RT3: back to canonical, folding in the CNOT-ring permutation F
        #pragma unroll
        for (int k = 0; k < PER_T; ++k) st[swz((k << 8) | tid)] = r[k];
        __syncthreads();

        const int rr = (l % (WIRES - 1)) + 1;
        int cols[WIRES];
        #pragma unroll
        for (int j = 0; j < WIRES; ++j) {
            int v = 1 << j;
            #pragma unroll
            for (int kk = WIRES - 1; kk >= 0; --kk) {   // g11 innermost
                int bc = 11 - kk;                       // control bit
                int bt = 11 - ((kk + rr) % WIRES);      // target bit
                v ^= ((v >> bc) & 1) << bt;
            }
            cols[j] = v;
        }
        int Ft = 0;
        #pragma unroll
        for (int j = 4; j < 12; ++j)
            if ((tid >> (j - 4)) & 1) Ft ^= cols[j];

        #pragma unroll
        for (int k = 0; k < PER_T; ++k) {
            int fk = ((k & 1) ? cols[0] : 0) ^ ((k & 2) ? cols[1] : 0) ^
                     ((k & 4) ? cols[2] : 0) ^ ((k & 8) ? cols[3] : 0);
            r[k] = st[swz(Ft ^ fk)];
        }
        __syncthreads();
    }

    // ---- write out ----
    if (write_mode == 0) {
        // harness views complex output as float32 real part: out_size = B*4096
        float4* ob4 = (float4*)(out + (size_t)b * NSTATE);
        #pragma unroll
        for (int c4 = 0; c4 < 4; ++c4)
            ob4[tid * 4 + c4] = make_float4(r[4*c4+0].x, r[4*c4+1].x,
                                            r[4*c4+2].x, r[4*c4+3].x);
    } else {
        float2* ob = (float2*)out + (size_t)b * NSTATE + tid * PER_T;
        #pragma unroll
        for (int k = 0; k < PER_T; ++k) ob[k] = r[k];
    }
}

extern "C" void kernel_launch(void* const* d_in, const int* in_sizes, int n_in,
                              void* d_out, int out_size, void* d_ws, size_t ws_size,
                              hipStream_t stream) {
    const float* x    = (const float*)d_in[0];
    const float* wts  = (const float*)d_in[1];
    const int*   reps = (const int*)d_in[2];
    float*       out  = (float*)d_out;
    (void)in_sizes; (void)n_in; (void)d_ws; (void)ws_size;

    const int write_mode = (out_size >= 2 * 1024 * NSTATE) ? 1 : 0;

    qsim_kernel<<<1024, BLOCK, 0, stream>>>(x, wts, reps, out, write_mode);
}

// Round 4
// 179.690 us; speedup vs baseline: 1.4895x; 1.2632x over previous
//
#include <hip/hip_runtime.h>

#define WIRES   12
#define NSTATE  4096          // 2^12
#define QDEPTH  8
#define BLOCK   256
#define PER_T   16            // amplitudes per thread (4 local index bits)

using f2 = __attribute__((ext_vector_type(2))) float;

// XOR swizzle on float2-granular LDS index: spreads every access pattern
// ~uniformly over the 16 float2 bank-columns (<=4 lanes/column for the hot
// patterns = b64 conflict-free minimum).
__device__ __forceinline__ int swz(int i) { return i ^ ((i >> 4) & 0xF); }

// Column j of the GF(2)-linear CNOT-ring permutation of layer l:
// F = g_0∘g_1∘...∘g_11 (g_11 applied first / innermost).
constexpr int colF(int l, int j) {
    int rr = (l % (WIRES - 1)) + 1;
    int v = 1 << j;
    for (int k = WIRES - 1; k >= 0; --k) {
        int bc = 11 - k;                   // control bit
        int bt = 11 - ((k + rr) % WIRES);  // target bit
        v ^= ((v >> bc) & 1) << bt;
    }
    return v;
}

// 2x2 complex gate on local register bit P. Complex mul written as
// scalar*f2 + scalar*perp(f2) so the SLP vectorizer forms v_pk_fma_f32.
template<int P>
__device__ __forceinline__ void gate(f2 r[PER_T], const float* __restrict__ mrow)
{
    const float4 A = ((const float4*)mrow)[0];   // u00r,u00i,u01r,u01i
    const float4 B = ((const float4*)mrow)[1];   // u10r,u10i,u11r,u11i
    #pragma unroll
    for (int pr = 0; pr < 8; ++pr) {
        const int k0 = ((pr >> P) << (P + 1)) | (pr & ((1 << P) - 1));
        const int k1 = k0 | (1 << P);
        const f2 s0 = r[k0], s1 = r[k1];
        const f2 p0 = f2{-s0.y, s0.x};
        const f2 p1 = f2{-s1.y, s1.x};
        r[k0] = A.x * s0 + A.y * p0 + A.z * s1 + A.w * p1;
        r[k1] = B.x * s0 + B.y * p0 + B.z * s1 + B.w * p1;
    }
}

// One SEL layer. Layout invariant: on entry and exit r[k] = amp[(tid<<4)|k].
// 3 LDS round-trips localize bit groups 7-4 and 11-8, the third one folds in
// the compile-time CNOT permutation F while returning to canonical layout.
template<int L>
__device__ __forceinline__ void do_layer(f2* __restrict__ st, f2 r[PER_T],
                                         const float* __restrict__ Mb,
                                         int tid, int thi, int tlo)
{
    const float* M = Mb + L * WIRES * 8;

    // Phase A: index bits 3..0 local = wires 8..11
    gate<3>(r, M + 8*8);  gate<2>(r, M + 9*8);
    gate<1>(r, M + 10*8); gate<0>(r, M + 11*8);

    #pragma unroll
    for (int k = 0; k < PER_T; ++k) st[swz((tid << 4) | k)] = r[k];
    __syncthreads();
    #pragma unroll
    for (int k = 0; k < PER_T; ++k) r[k] = st[swz((thi << 8) | (k << 4) | tlo)];
    __syncthreads();

    // Phase B: index bits 7..4 local = wires 4..7
    gate<3>(r, M + 4*8); gate<2>(r, M + 5*8);
    gate<1>(r, M + 6*8); gate<0>(r, M + 7*8);

    #pragma unroll
    for (int k = 0; k < PER_T; ++k) st[swz((thi << 8) | (k << 4) | tlo)] = r[k];
    __syncthreads();
    #pragma unroll
    for (int k = 0; k < PER_T; ++k) r[k] = st[swz((k << 8) | tid)];
    __syncthreads();

    // Phase C: index bits 11..8 local = wires 0..3
    gate<3>(r, M + 0*8); gate<2>(r, M + 1*8);
    gate<1>(r, M + 2*8); gate<0>(r, M + 3*8);

    #pragma unroll
    for (int k = 0; k < PER_T; ++k) st[swz((k << 8) | tid)] = r[k];
    __syncthreads();

    // Gather with F (all masks are compile-time constants)
    int Ft = 0;
    #pragma unroll
    for (int j = 0; j < 8; ++j) {
        const int Cj = colF(L, 4 + j);
        Ft ^= ((tid >> j) & 1) ? Cj : 0;
    }
    #pragma unroll
    for (int k = 0; k < PER_T; ++k) {
        const int fk = ((k & 1) ? colF(L, 0) : 0) ^ ((k & 2) ? colF(L, 1) : 0) ^
                       ((k & 4) ? colF(L, 2) : 0) ^ ((k & 8) ? colF(L, 3) : 0);
        r[k] = st[swz(Ft ^ fk)];
    }
    __syncthreads();
}

__global__ __launch_bounds__(BLOCK, 4) void qsim_kernel(
    const float* __restrict__ x,
    const float* __restrict__ wts,
    const int*   __restrict__ reps_ptr,
    float*       __restrict__ out,
    int write_mode)
{
    __shared__ f2 st[NSTATE];                               // 32 KB
    __shared__ __align__(16) float mats[QDEPTH * WIRES][8]; // 3 KB

    const int tid = threadIdx.x;
    const int b   = blockIdx.x;
    const int thi = tid >> 4, tlo = tid & 15;

    // ---- rotation matrices from tanh(weights), one per thread (96) ----
    if (tid < QDEPTH * WIRES) {
        float phi   = tanhf(wts[tid * 3 + 0]);
        float theta = tanhf(wts[tid * 3 + 1]);
        float omega = tanhf(wts[tid * 3 + 2]);
        float c  = cosf(theta * 0.5f);
        float s  = sinf(theta * 0.5f);
        float a  = 0.5f * (phi + omega);
        float bm = 0.5f * (phi - omega);
        float ca = cosf(a),  sa = sinf(a);
        float cb = cosf(bm), sb = sinf(bm);
        mats[tid][0] =  c * ca;   // U00 = e^{-ia} c
        mats[tid][1] = -c * sa;
        mats[tid][2] = -s * cb;   // U01 = -conj(em) s
        mats[tid][3] = -s * sb;
        mats[tid][4] =  s * cb;   // U10 = em s
        mats[tid][5] = -s * sb;
        mats[tid][6] =  c * ca;   // U11 = conj(ep) c
        mats[tid][7] =  c * sa;
    }

    // ---- coalesced load of x, staged through LDS as packed real pairs ----
    // pair p holds reals of amps (2p, 2p+1)
    const float4* xb4 = (const float4*)(x + (size_t)b * NSTATE);
    #pragma unroll
    for (int c4 = 0; c4 < 4; ++c4) {
        int g = c4 * BLOCK + tid;            // coalesced float4 index
        float4 v = xb4[g];
        st[swz(2 * g)]     = f2{v.x, v.y};
        st[swz(2 * g + 1)] = f2{v.z, v.w};
    }
    __syncthreads();                          // mats + staging visible

    f2 r[PER_T];
    #pragma unroll
    for (int m = 0; m < 8; ++m) {
        f2 pr = st[swz(tid * 8 + m)];
        r[2*m]   = f2{pr.x, 0.f};
        r[2*m+1] = f2{pr.y, 0.f};
    }
    __syncthreads();                          // unpack reads done before RT1

    const int reps = reps_ptr[0];
    const float* Mb = &mats[0][0];
    for (int rep = 0; rep < reps; ++rep) {
        do_layer<0>(st, r, Mb, tid, thi, tlo);
        do_layer<1>(st, r, Mb, tid, thi, tlo);
        do_layer<2>(st, r, Mb, tid, thi, tlo);
        do_layer<3>(st, r, Mb, tid, thi, tlo);
        do_layer<4>(st, r, Mb, tid, thi, tlo);
        do_layer<5>(st, r, Mb, tid, thi, tlo);
        do_layer<6>(st, r, Mb, tid, thi, tlo);
        do_layer<7>(st, r, Mb, tid, thi, tlo);
    }

    // ---- write out ----
    if (write_mode == 0) {
        // pack real parts into pairs, then coalesced float4 stores
        #pragma unroll
        for (int m = 0; m < 8; ++m)
            st[swz(tid * 8 + m)] = f2{r[2*m].x, r[2*m+1].x};
        __syncthreads();
        float4* ob4 = (float4*)(out + (size_t)b * NSTATE);
        #pragma unroll
        for (int c4 = 0; c4 < 4; ++c4) {
            int g = c4 * BLOCK + tid;
            f2 a  = st[swz(2 * g)];
            f2 b2 = st[swz(2 * g + 1)];
            ob4[g] = make_float4(a.x, a.y, b2.x, b2.y);
        }
    } else {
        float2* ob = (float2*)out + (size_t)b * NSTATE + tid * PER_T;
        #pragma unroll
        for (int k = 0; k < PER_T; ++k) ob[k] = make_float2(r[k].x, r[k].y);
    }
}

extern "C" void kernel_launch(void* const* d_in, const int* in_sizes, int n_in,
                              void* d_out, int out_size, void* d_ws, size_t ws_size,
                              hipStream_t stream) {
    const float* x    = (const float*)d_in[0];
    const float* wts  = (const float*)d_in[1];
    const int*   reps = (const int*)d_in[2];
    float*       out  = (float*)d_out;
    (void)in_sizes; (void)n_in; (void)d_ws; (void)ws_size;

    const int write_mode = (out_size >= 2 * 1024 * NSTATE) ? 1 : 0;

    qsim_kernel<<<1024, BLOCK, 0, stream>>>(x, wts, reps, out, write_mode);
}

// Round 5
// 167.123 us; speedup vs baseline: 1.6015x; 1.0752x over previous
//
#include <hip/hip_runtime.h>

#define WIRES   12
#define NSTATE  4096          // 2^12
#define QDEPTH  8
#define BLOCK   64            // ONE wave per block = one batch element
#define PER_T   64            // 6 local index bits; state in 128 VGPRs

using f2 = __attribute__((ext_vector_type(2))) float;

// Padded LDS layout: element i (0..4095) lives at f2-slot i + (i>>6)
// (row pitch 65). All structured row/col patterns are conflict-free and
// their addresses are base + compile-time immediate.
__device__ __forceinline__ int pad(int i) { return i + (i >> 6); }

// Column j of the GF(2)-linear CNOT-ring permutation of layer l:
// F = g_0∘g_1∘...∘g_11 (g_11 applied first / innermost).
constexpr int colF(int l, int j) {
    int rr = (l % (WIRES - 1)) + 1;
    int v = 1 << j;
    for (int k = WIRES - 1; k >= 0; --k) {
        int bc = 11 - k;                   // control bit
        int bt = 11 - ((k + rr) % WIRES);  // target bit
        v ^= ((v >> bc) & 1) << bt;
    }
    return v;
}
struct ColsT { int v[QDEPTH][WIRES]; };
constexpr ColsT mkCols() {
    ColsT c{};
    for (int l = 0; l < QDEPTH; ++l)
        for (int j = 0; j < WIRES; ++j) c.v[l][j] = colF(l, j);
    return c;
}
static __device__ const ColsT COLS = mkCols();   // rodata, uniform s_load

// 2x2 complex gate on local register bit P (compile-time => static reg idx).
// Written scalar*f2 + scalar*perp(f2) so the backend forms v_pk_fma_f32.
template<int P>
__device__ __forceinline__ void gate(f2 r[PER_T], const float* __restrict__ m)
{
    const float4 A = ((const float4*)m)[0];   // u00r,u00i,u01r,u01i
    const float4 B = ((const float4*)m)[1];   // u10r,u10i,u11r,u11i
    #pragma unroll
    for (int pr = 0; pr < PER_T / 2; ++pr) {
        const int k0 = ((pr >> P) << (P + 1)) | (pr & ((1 << P) - 1));
        const int k1 = k0 | (1 << P);
        const f2 s0 = r[k0], s1 = r[k1];
        const f2 p0 = f2{-s0.y, s0.x};
        const f2 p1 = f2{-s1.y, s1.x};
        r[k0] = A.x * s0 + A.y * p0 + A.z * s1 + A.w * p1;
        r[k1] = B.x * s0 + B.y * p0 + B.z * s1 + B.w * p1;
    }
}

// One wave = one batch element. State: r[k] = amp[(lane<<6)|k] (canonical).
// Per layer: 6 gates in regs (wires 6..11) -> LDS transpose -> 6 gates
// (wires 0..5) -> LDS gather folding the CNOT permutation F back to
// canonical. NO __syncthreads anywhere: single-wave blocks, compiler
// lgkmcnt ordering handles all LDS dependencies.
__global__ __launch_bounds__(BLOCK, 2) void qsim_kernel(
    const float* __restrict__ x,
    const float* __restrict__ wts,
    const int*   __restrict__ reps_ptr,
    float*       __restrict__ out,
    int write_mode)
{
    __shared__ f2 st[65 * 64];                              // 33280 B
    __shared__ __align__(16) float mats[QDEPTH * WIRES][8]; // 3 KB

    const int lane = threadIdx.x;
    const int b    = blockIdx.x;

    // ---- rotation matrices from tanh(weights) (96 mats, 64 lanes: loop) ----
    for (int t = lane; t < QDEPTH * WIRES; t += BLOCK) {
        float phi   = tanhf(wts[t * 3 + 0]);
        float theta = tanhf(wts[t * 3 + 1]);
        float omega = tanhf(wts[t * 3 + 2]);
        float c  = cosf(theta * 0.5f);
        float s  = sinf(theta * 0.5f);
        float a  = 0.5f * (phi + omega);
        float bm = 0.5f * (phi - omega);
        float ca = cosf(a),  sa = sinf(a);
        float cb = cosf(bm), sb = sinf(bm);
        mats[t][0] =  c * ca;   // U00 = e^{-ia} c
        mats[t][1] = -c * sa;
        mats[t][2] = -s * cb;   // U01 = -conj(em) s
        mats[t][3] = -s * sb;
        mats[t][4] =  s * cb;   // U10 = em s
        mats[t][5] = -s * sb;
        mats[t][6] =  c * ca;   // U11 = conj(ep) c
        mats[t][7] =  c * sa;
    }

    // ---- coalesced load of x, staged via LDS as packed real pairs ----
    const float4* xb4 = (const float4*)(x + (size_t)b * NSTATE);
    #pragma unroll
    for (int c = 0; c < 16; ++c) {
        int g = c * BLOCK + lane;            // coalesced float4 index
        float4 v = xb4[g];
        st[pad(2 * g)]     = f2{v.x, v.y};   // pair p = amps(2p,2p+1) reals
        st[pad(2 * g + 1)] = f2{v.z, v.w};
    }
    f2 r[PER_T];
    #pragma unroll
    for (int m = 0; m < 32; ++m) {
        f2 pr2 = st[pad((lane << 5) | m)];
        r[2*m]   = f2{pr2.x, 0.f};
        r[2*m+1] = f2{pr2.y, 0.f};
    }

    const int reps = reps_ptr[0];
    for (int rep = 0; rep < reps; ++rep) {
        #pragma unroll 1
        for (int l = 0; l < QDEPTH; ++l) {
            const float* M = &mats[l * WIRES][0];

            // Phase A: wires 6..11 on local bits 5..0 (bit = 11-wire)
            gate<5>(r, M + 6*8);  gate<4>(r, M + 7*8);
            gate<3>(r, M + 8*8);  gate<2>(r, M + 9*8);
            gate<1>(r, M + 10*8); gate<0>(r, M + 11*8);

            // RT1: canonical -> hi-bits-local (addresses = base + imm)
            #pragma unroll
            for (int k = 0; k < PER_T; ++k) st[65 * lane + k] = r[k];
            #pragma unroll
            for (int k = 0; k < PER_T; ++k) r[k] = st[65 * k + lane];
            // now r[k] = amp[(k<<6)|lane]

            // Phase B: wires 0..5 on local bits 5..0 (local bit = 5-wire)
            gate<5>(r, M + 0*8); gate<4>(r, M + 1*8);
            gate<3>(r, M + 2*8); gate<2>(r, M + 3*8);
            gate<1>(r, M + 4*8); gate<0>(r, M + 5*8);

            // RT2: store hi-local, gather canonical ∘ F (CNOT ring)
            #pragma unroll
            for (int k = 0; k < PER_T; ++k) st[65 * k + lane] = r[k];

            const int c0 = COLS.v[l][0], c1 = COLS.v[l][1], c2 = COLS.v[l][2];
            const int c3 = COLS.v[l][3], c4 = COLS.v[l][4], c5 = COLS.v[l][5];
            int Ft = 0;
            #pragma unroll
            for (int j = 0; j < 6; ++j)
                Ft ^= ((lane >> j) & 1) ? COLS.v[l][6 + j] : 0;
            #pragma unroll
            for (int k = 0; k < PER_T; ++k) {
                int ck = ((k & 1)  ? c0 : 0) ^ ((k & 2)  ? c1 : 0) ^
                         ((k & 4)  ? c2 : 0) ^ ((k & 8)  ? c3 : 0) ^
                         ((k & 16) ? c4 : 0) ^ ((k & 32) ? c5 : 0);
                r[k] = st[pad(Ft ^ ck)];
            }
            // r[k] = amp_after_layer[(lane<<6)|k]  (canonical again)
        }
    }

    // ---- write out ----
    if (write_mode == 0) {
        // harness views complex output as float32 real part
        #pragma unroll
        for (int m = 0; m < 32; ++m)
            st[pad((lane << 5) | m)] = f2{r[2*m].x, r[2*m+1].x};
        float4* ob4 = (float4*)(out + (size_t)b * NSTATE);
        #pragma unroll
        for (int c = 0; c < 16; ++c) {
            int g = c * BLOCK + lane;
            f2 a  = st[pad(2 * g)];
            f2 b2 = st[pad(2 * g + 1)];
            ob4[g] = make_float4(a.x, a.y, b2.x, b2.y);
        }
    } else {
        float2* ob = (float2*)out + (size_t)b * NSTATE;
        #pragma unroll
        for (int k = 0; k < PER_T; ++k)
            ob[(lane << 6) | k] = make_float2(r[k].x, r[k].y);
    }
}

extern "C" void kernel_launch(void* const* d_in, const int* in_sizes, int n_in,
                              void* d_out, int out_size, void* d_ws, size_t ws_size,
                              hipStream_t stream) {
    const float* x    = (const float*)d_in[0];
    const float* wts  = (const float*)d_in[1];
    const int*   reps = (const int*)d_in[2];
    float*       out  = (float*)d_out;
    (void)in_sizes; (void)n_in; (void)d_ws; (void)ws_size;

    const int write_mode = (out_size >= 2 * 1024 * NSTATE) ? 1 : 0;

    qsim_kernel<<<1024, BLOCK, 0, stream>>>(x, wts, reps, out, write_mode);
}